// Round 10
// baseline (983.831 us; speedup 1.0000x reference)
//
#include <hip/hip_runtime.h>
#include <math.h>

#define NN 10000
#define NFEAT 512
#define NHID 256
#define NCLASS 40
#define NLAYERS 8
#define MAXDEG 96
#define GPASS 4           // measurement: 1 real + 3 zero-scaled gather passes

#define CVX_BLOCKS 5000   // convert_x   : 1,280,000 float4 / 256
#define PW_BLOCKS  2560   // prep_weights:   655,360 idx   / 256
#define PE_BLOCKS  3750   // prep_ell    :   960,000 idx   / 256

typedef __attribute__((ext_vector_type(8))) short bf16x8;
typedef __attribute__((ext_vector_type(4))) float floatx4;
typedef __attribute__((ext_vector_type(2))) float floatx2;
typedef __attribute__((ext_vector_type(4))) unsigned short ushort4v;

__device__ __forceinline__ unsigned short f2bf(float f) {
    union { float f; unsigned int u; } v; v.f = f;
    unsigned int r = v.u + 0x7fffu + ((v.u >> 16) & 1u);  // RNE
    return (unsigned short)(r >> 16);
}
__device__ __forceinline__ float bf2f(unsigned short h) {
    union { unsigned int u; float f; } v; v.u = ((unsigned int)h) << 16;
    return v.f;
}
__device__ __forceinline__ unsigned char f2fp8(float f) {
    return (unsigned char)(__builtin_amdgcn_cvt_pk_fp8_f32(f, f, 0, false) & 0xFF);
}

// ---------------------------------------------------------------------------
// build_graph: one block per row; one pass over the 400MB dense adjacency.
// ---------------------------------------------------------------------------
__global__ __launch_bounds__(256) void build_graph(const float* __restrict__ adj,
                                                   int* __restrict__ cnt,
                                                   int* __restrict__ ell,
                                                   float* __restrict__ dinv) {
    int i = blockIdx.x;
    __shared__ int scnt;
    if (threadIdx.x == 0) scnt = 0;
    __syncthreads();
    const float4* row = (const float4*)(adj + (size_t)i * NN);
    int* erow = ell + (size_t)i * MAXDEG;
    for (int f = threadIdx.x; f < NN / 4; f += 256) {
        float4 v = row[f];
        if (v.x != 0.0f) { int s = atomicAdd(&scnt, 1); if (s < MAXDEG) erow[s] = 4*f + 0; }
        if (v.y != 0.0f) { int s = atomicAdd(&scnt, 1); if (s < MAXDEG) erow[s] = 4*f + 1; }
        if (v.z != 0.0f) { int s = atomicAdd(&scnt, 1); if (s < MAXDEG) erow[s] = 4*f + 2; }
        if (v.w != 0.0f) { int s = atomicAdd(&scnt, 1); if (s < MAXDEG) erow[s] = 4*f + 3; }
    }
    __syncthreads();
    if (threadIdx.x == 0) {
        int c = scnt;
        cnt[i] = (c < MAXDEG) ? c : MAXDEG;
        dinv[i] = rsqrtf(1.0f + (float)c);
    }
}

// ---------------------------------------------------------------------------
// prep_all: convert_x + prep_weights + prep_ell merged (blockIdx-range split).
// ---------------------------------------------------------------------------
__global__ __launch_bounds__(256) void prep_all(const float* __restrict__ x,
                                                unsigned short* __restrict__ xb,
                                                const float* __restrict__ w0,
                                                const float* __restrict__ cw,
                                                unsigned short* __restrict__ w0t,
                                                unsigned short* __restrict__ Mt,
                                                const int* __restrict__ ell,
                                                const int* __restrict__ cnt,
                                                const float* __restrict__ dinv,
                                                int2* __restrict__ es) {
    int b = blockIdx.x, t = threadIdx.x;
    if (b < CVX_BLOCKS) {
        int idx = b * 256 + t;
        float4 v = ((const float4*)x)[idx];
        ushort4v o;
        o.x = f2bf(v.x); o.y = f2bf(v.y); o.z = f2bf(v.z); o.w = f2bf(v.w);
        ((ushort4v*)xb)[idx] = o;
    } else if (b < CVX_BLOCKS + PW_BLOCKS) {
        int idx = (b - CVX_BLOCKS) * 256 + t;
        if (idx < 131072) {
            int n = idx >> 9, k = idx & 511;
            w0t[idx] = f2bf(w0[(size_t)k * 256 + n]);
        } else {
            int j = idx - 131072;
            int l = j >> 16;
            int r = j & 65535;
            int n = r >> 8, k = r & 255;
            float theta = logf(0.5f / (float)(l + 1) + 1.0f);
            float v = theta * cw[(size_t)l * 65536 + (size_t)k * 256 + n];
            if (k == n) v += 1.0f - theta;
            Mt[j] = f2bf(v);
        }
    } else {
        int idx = (b - CVX_BLOCKS - PW_BLOCKS) * 256 + t;   // < 960000
        if (idx >= NN * MAXDEG) return;
        int i = idx / MAXDEG, e = idx % MAXDEG;
        int2 v; v.x = 0; v.y = 0;                            // pad: row 0, x0.0
        if (e < cnt[i]) {
            int j = ell[idx];
            v.x = j; v.y = __float_as_int(dinv[j]);
        }
        es[idx] = v;
    }
}

// ---------------------------------------------------------------------------
// gemm0: h0 = relu(x @ w0 + b0); bf16 h0b AND fp8 h08 (fused convert).
// ---------------------------------------------------------------------------
__global__ __launch_bounds__(512, 4) void gemm0_mfma(const unsigned short* __restrict__ xb,
                                                     const unsigned short* __restrict__ w0t,
                                                     const float* __restrict__ b0,
                                                     unsigned short* __restrict__ h0b,
                                                     unsigned char* __restrict__ h8o) {
    int t = threadIdx.x, wv = t >> 6, lane = t & 63;
    int lrow = lane & 15, quad = lane >> 4;
    int r0 = blockIdx.x * 16;

    bf16x8 a[16];
    const unsigned short* arow = xb + (size_t)(r0 + lrow) * NFEAT + quad * 8;
    #pragma unroll
    for (int f = 0; f < 16; ++f)
        a[f] = *(const bf16x8*)(arow + f * 32);

    #pragma unroll 1
    for (int n = 0; n < 2; ++n) {
        int nt = wv * 2 + n;
        floatx4 acc = {0.f, 0.f, 0.f, 0.f};
        const unsigned short* wrow = w0t + (size_t)(nt * 16 + lrow) * NFEAT + quad * 8;
        #pragma unroll
        for (int f = 0; f < 16; ++f) {
            bf16x8 bb = *(const bf16x8*)(wrow + f * 32);
            acc = __builtin_amdgcn_mfma_f32_16x16x32_bf16(a[f], bb, acc, 0, 0, 0);
        }
        int col = nt * 16 + lrow;
        float bias = b0[col];
        #pragma unroll
        for (int r = 0; r < 4; ++r) {
            int row = r0 + quad * 4 + r;
            unsigned short bv = f2bf(fmaxf(acc[r] + bias, 0.f));
            h0b[(size_t)row * NHID + col] = bv;
            h8o[(size_t)row * NHID + col] = f2fp8(bf2f(bv));
        }
    }
}

// ---------------------------------------------------------------------------
// gather pipeline helpers (R7's half-group ping-pong, 32-VGPR staging).
// proc_hg applies opaque multiplier m (measurement: m=1 real, m=0 replay).
// ---------------------------------------------------------------------------
__device__ __forceinline__ void load_hg(const int2* __restrict__ e0r,
                                        const int2* __restrict__ e1r,
                                        const unsigned int* __restrict__ h8,
                                        int lane, int base,
                                        unsigned int (&x0)[4], unsigned int (&x1)[4],
                                        float (&s0)[4], float (&s1)[4]) {
    #pragma unroll
    for (int u = 0; u < 4; ++u) {
        int2 p = e0r[base + u];            // uniform -> s_load_dwordx2
        int2 q = e1r[base + u];
        s0[u] = __int_as_float(p.y);
        s1[u] = __int_as_float(q.y);
        x0[u] = h8[(size_t)p.x * 64 + lane];
        x1[u] = h8[(size_t)q.x * 64 + lane];
    }
}

__device__ __forceinline__ void proc_hg(const unsigned int (&x0)[4],
                                        const unsigned int (&x1)[4],
                                        const float (&s0)[4], const float (&s1)[4],
                                        float m, float4& a0, float4& a1) {
    #pragma unroll
    for (int u = 0; u < 4; ++u) {
        floatx2 lo = __builtin_amdgcn_cvt_pk_f32_fp8(x0[u], false);
        floatx2 hi = __builtin_amdgcn_cvt_pk_f32_fp8(x0[u], true);
        a0.x = fmaf(m * s0[u], lo.x, a0.x);
        a0.y = fmaf(m * s0[u], lo.y, a0.y);
        a0.z = fmaf(m * s0[u], hi.x, a0.z);
        a0.w = fmaf(m * s0[u], hi.y, a0.w);
        lo = __builtin_amdgcn_cvt_pk_f32_fp8(x1[u], false);
        hi = __builtin_amdgcn_cvt_pk_f32_fp8(x1[u], true);
        a1.x = fmaf(m * s1[u], lo.x, a1.x);
        a1.y = fmaf(m * s1[u], lo.y, a1.y);
        a1.z = fmaf(m * s1[u], hi.x, a1.z);
        a1.w = fmaf(m * s1[u], hi.y, a1.w);
    }
}

// ---------------------------------------------------------------------------
// layer_fused: EXACTLY R7 (777.7us best) except the edge-gather loop runs
// GPASS times: pass 0 with m=1.0 (real), passes 1..3 with m=0.0 — same
// loads, same addresses, fma adds +0.0 -> bit-identical output.  m is
// opaqued via inline asm so the compiler can neither fold 0*s nor DCE the
// replay loads.  dur_us delta / (NLAYERS*(GPASS-1)) = true per-layer gather
// cost -> decides gather-bound vs overhead-bound for the next round.
// ---------------------------------------------------------------------------
template<bool LAST>
__global__ __launch_bounds__(512, 6) void layer_fused(const unsigned int* __restrict__ h8,
                                                      const unsigned short* __restrict__ h0b,
                                                      const float* __restrict__ dinv,
                                                      const int* __restrict__ cnt,
                                                      const int2* __restrict__ es,
                                                      const unsigned short* __restrict__ Mt,
                                                      const float* __restrict__ w1,
                                                      const float* __restrict__ b1,
                                                      unsigned char* __restrict__ h8_out,
                                                      float* __restrict__ out) {
    __shared__ unsigned short supb[16][264];
    __shared__ float hs[LAST ? 16 * 264 : 4];

    int t = threadIdx.x;
    int wv = __builtin_amdgcn_readfirstlane(t >> 6);
    int lane = t & 63;
    int r0 = blockIdx.x * 16;

    int lr0 = wv * 2, lr1 = lr0 + 1;
    int i0 = r0 + lr0, i1 = r0 + lr1;

    unsigned int su0 = h8[(size_t)i0 * 64 + lane];
    unsigned int su1 = h8[(size_t)i1 * 64 + lane];
    ushort4v h0v0 = ((const ushort4v*)h0b)[(size_t)i0 * 64 + lane];
    ushort4v h0v1 = ((const ushort4v*)h0b)[(size_t)i1 * 64 + lane];

    float di0 = dinv[i0], di1 = dinv[i1];
    int dA = (cnt[i0] + 7) & ~7, dB = (cnt[i1] + 7) & ~7;
    int dm = dA > dB ? dA : dB;
    const int2* e0r = es + (size_t)i0 * MAXDEG;
    const int2* e1r = es + (size_t)i1 * MAXDEG;

    floatx2 slo = __builtin_amdgcn_cvt_pk_f32_fp8(su0, false);
    floatx2 shi = __builtin_amdgcn_cvt_pk_f32_fp8(su0, true);
    float4 a0, a1;
    a0.x = di0 * slo.x; a0.y = di0 * slo.y; a0.z = di0 * shi.x; a0.w = di0 * shi.y;
    slo = __builtin_amdgcn_cvt_pk_f32_fp8(su1, false);
    shi = __builtin_amdgcn_cvt_pk_f32_fp8(su1, true);
    a1.x = di1 * slo.x; a1.y = di1 * slo.y; a1.z = di1 * shi.x; a1.w = di1 * shi.y;

    int nh = dm >> 2;
    #pragma unroll 1
    for (int pass = 0; pass < GPASS; ++pass) {
        float m = (pass == 0) ? 1.0f : 0.0f;
        asm volatile("" : "+v"(m));                 // opaque: no fold, no DCE
        unsigned int xA0[4], xA1[4], xB0[4], xB1[4];
        float sA0[4], sA1[4], sB0[4], sB1[4];
        if (nh > 0) {
            load_hg(e0r, e1r, h8, lane, 0, xA0, xA1, sA0, sA1);
            bool useA = true;
            #pragma unroll 1
            for (int g = 1; g < nh; ++g) {
                if (useA) {
                    load_hg(e0r, e1r, h8, lane, g << 2, xB0, xB1, sB0, sB1);
                    proc_hg(xA0, xA1, sA0, sA1, m, a0, a1);
                } else {
                    load_hg(e0r, e1r, h8, lane, g << 2, xA0, xA1, sA0, sA1);
                    proc_hg(xB0, xB1, sB0, sB1, m, a0, a1);
                }
                useA = !useA;
            }
            if (useA) proc_hg(xA0, xA1, sA0, sA1, m, a0, a1);
            else      proc_hg(xB0, xB1, sB0, sB1, m, a0, a1);
        }
    }

    ushort4v ob;
    ob.x = f2bf(0.9f * (di0 * a0.x) + 0.1f * bf2f(h0v0.x));
    ob.y = f2bf(0.9f * (di0 * a0.y) + 0.1f * bf2f(h0v0.y));
    ob.z = f2bf(0.9f * (di0 * a0.z) + 0.1f * bf2f(h0v0.z));
    ob.w = f2bf(0.9f * (di0 * a0.w) + 0.1f * bf2f(h0v0.w));
    *(ushort4v*)&supb[lr0][4 * lane] = ob;
    ob.x = f2bf(0.9f * (di1 * a1.x) + 0.1f * bf2f(h0v1.x));
    ob.y = f2bf(0.9f * (di1 * a1.y) + 0.1f * bf2f(h0v1.y));
    ob.z = f2bf(0.9f * (di1 * a1.z) + 0.1f * bf2f(h0v1.z));
    ob.w = f2bf(0.9f * (di1 * a1.w) + 0.1f * bf2f(h0v1.w));
    *(ushort4v*)&supb[lr1][4 * lane] = ob;
    __syncthreads();

    // ---- phase 2: MFMA GEMM (residual folded in M) ----
    int lrow = lane & 15, quad = lane >> 4;
    bf16x8 a[8];
    #pragma unroll
    for (int f = 0; f < 8; ++f)
        a[f] = *(const bf16x8*)&supb[lrow][quad * 8 + f * 32];

    #pragma unroll 1
    for (int n = 0; n < 2; ++n) {
        int nt = wv * 2 + n;
        floatx4 acc = {0.f, 0.f, 0.f, 0.f};
        const unsigned short* wrow = Mt + (size_t)(nt * 16 + lrow) * NHID + quad * 8;
        #pragma unroll
        for (int f = 0; f < 8; ++f) {
            bf16x8 b = *(const bf16x8*)(wrow + f * 32);
            acc = __builtin_amdgcn_mfma_f32_16x16x32_bf16(a[f], b, acc, 0, 0, 0);
        }
        int col = nt * 16 + lrow;
        #pragma unroll
        for (int r = 0; r < 4; ++r) {
            int lr2 = quad * 4 + r;
            float o = fmaxf(acc[r], 0.f);
            if (LAST) {
                hs[lr2 * 264 + col] = o;
            } else {
                h8_out[(size_t)(r0 + lr2) * NHID + col] = f2fp8(o);
            }
        }
    }

    // ---- phase 3 (LAST only): logits + log_softmax ----
    if (LAST) {
        __syncthreads();
        #pragma unroll 1
        for (int rr = 0; rr < 2; ++rr) {
            int lr = wv * 2 + rr;
            const float* hr = hs + lr * 264;
            float logit = -1e30f;
            if (lane < NCLASS) {
                float acc = b1[lane];
                #pragma unroll 8
                for (int k = 0; k < NHID; ++k)
                    acc = fmaf(hr[k], w1[k * NCLASS + lane], acc);
                logit = acc;
            }
            float m2 = logit;
            #pragma unroll
            for (int off = 32; off > 0; off >>= 1)
                m2 = fmaxf(m2, __shfl_xor(m2, off, 64));
            float e = (lane < NCLASS) ? expf(logit - m2) : 0.0f;
            float ssum = e;
            #pragma unroll
            for (int off = 32; off > 0; off >>= 1)
                ssum += __shfl_xor(ssum, off, 64);
            float lse = m2 + logf(ssum);
            if (lane < NCLASS)
                out[(size_t)(r0 + lr) * NCLASS + lane] = logit - lse;
        }
    }
}

// ---------------------------------------------------------------------------
extern "C" void kernel_launch(void* const* d_in, const int* in_sizes, int n_in,
                              void* d_out, int out_size, void* d_ws, size_t ws_size,
                              hipStream_t stream) {
    const float* x      = (const float*)d_in[0];
    const float* adj    = (const float*)d_in[1];
    const float* w0     = (const float*)d_in[2];
    const float* b0     = (const float*)d_in[3];
    const float* conv_w = (const float*)d_in[4];
    const float* w1     = (const float*)d_in[5];
    const float* b1     = (const float*)d_in[6];
    float* out = (float*)d_out;

    char* ws = (char*)d_ws;
    size_t off = 0;
    auto alloc = [&](size_t bytes) -> void* {
        void* p = ws + off;
        off = (off + bytes + 255) & ~(size_t)255;
        return p;
    };
    float*          dinv  = (float*)alloc((size_t)NN * 4);
    int*            cnt   = (int*)  alloc((size_t)NN * 4);
    int*            ell   = (int*)  alloc((size_t)NN * MAXDEG * 4);
    int2*           es    = (int2*) alloc((size_t)NN * MAXDEG * 8);
    unsigned short* xb    = (unsigned short*)alloc((size_t)NN * NFEAT * 2);
    unsigned short* w0t   = (unsigned short*)alloc((size_t)NFEAT * NHID * 2);
    unsigned short* Mt    = (unsigned short*)alloc((size_t)NLAYERS * NHID * NHID * 2);
    unsigned short* h0b   = (unsigned short*)alloc((size_t)NN * NHID * 2);
    unsigned int*   h08   = (unsigned int*)alloc((size_t)NN * NHID);
    unsigned int*   hP8   = (unsigned int*)alloc((size_t)NN * NHID);
    unsigned int*   hQ8   = (unsigned int*)alloc((size_t)NN * NHID);

    build_graph<<<NN, 256, 0, stream>>>(adj, cnt, ell, dinv);
    prep_all<<<CVX_BLOCKS + PW_BLOCKS + PE_BLOCKS, 256, 0, stream>>>(
        x, xb, w0, conv_w, w0t, Mt, ell, cnt, dinv, es);
    gemm0_mfma<<<NN / 16, 512, 0, stream>>>(xb, w0t, b0, h0b, (unsigned char*)h08);

    const unsigned int* hc8 = h08;
    for (int l = 0; l < NLAYERS; ++l) {
        unsigned int* nxt = (l & 1) ? hQ8 : hP8;
        const unsigned short* wt = Mt + (size_t)l * NHID * NHID;
        if (l == NLAYERS - 1)
            layer_fused<true><<<NN / 16, 512, 0, stream>>>(hc8, h0b, dinv, cnt, es, wt, w1, b1, nullptr, out);
        else
            layer_fused<false><<<NN / 16, 512, 0, stream>>>(hc8, h0b, dinv, cnt, es, wt, nullptr, nullptr, (unsigned char*)nxt, nullptr);
        hc8 = nxt;
    }
}

// Round 11
// 890.960 us; speedup vs baseline: 1.1042x; 1.1042x over previous
//
#include <hip/hip_runtime.h>
#include <math.h>

#define NN 10000
#define NFEAT 512
#define NHID 256
#define NCLASS 40
#define NLAYERS 8
#define MAXDEG 96
#define ZROW NN           // dedicated all-zero h8 row for edge-list pads

#define CVX_BLOCKS 5000   // convert_x   : 1,280,000 float4 / 256
#define PW_BLOCKS  2560   // prep_weights:   655,360 idx   / 256
#define PE_BLOCKS  3750   // ell pads    :   960,000 idx   / 256
#define ZR_BLOCKS  1      // zero rows   :   192 words

typedef __attribute__((ext_vector_type(8))) short bf16x8;
typedef __attribute__((ext_vector_type(4))) float floatx4;
typedef __attribute__((ext_vector_type(2))) float floatx2;
typedef __attribute__((ext_vector_type(4))) unsigned short ushort4v;

__device__ __forceinline__ unsigned short f2bf(float f) {
    union { float f; unsigned int u; } v; v.f = f;
    unsigned int r = v.u + 0x7fffu + ((v.u >> 16) & 1u);  // RNE
    return (unsigned short)(r >> 16);
}
__device__ __forceinline__ float bf2f(unsigned short h) {
    union { unsigned int u; float f; } v; v.u = ((unsigned int)h) << 16;
    return v.f;
}
__device__ __forceinline__ unsigned char f2fp8(float f) {
    return (unsigned char)(__builtin_amdgcn_cvt_pk_fp8_f32(f, f, 0, false) & 0xFF);
}

// ---------------------------------------------------------------------------
// build_graph: one block per row; one pass over the 400MB dense adjacency.
// HBM-bound floor ~63us — irreducible.
// ---------------------------------------------------------------------------
__global__ __launch_bounds__(256) void build_graph(const float* __restrict__ adj,
                                                   int* __restrict__ cnt,
                                                   int* __restrict__ ell,
                                                   float* __restrict__ dinv) {
    int i = blockIdx.x;
    __shared__ int scnt;
    if (threadIdx.x == 0) scnt = 0;
    __syncthreads();
    const float4* row = (const float4*)(adj + (size_t)i * NN);
    int* erow = ell + (size_t)i * MAXDEG;
    for (int f = threadIdx.x; f < NN / 4; f += 256) {
        float4 v = row[f];
        if (v.x != 0.0f) { int s = atomicAdd(&scnt, 1); if (s < MAXDEG) erow[s] = 4*f + 0; }
        if (v.y != 0.0f) { int s = atomicAdd(&scnt, 1); if (s < MAXDEG) erow[s] = 4*f + 1; }
        if (v.z != 0.0f) { int s = atomicAdd(&scnt, 1); if (s < MAXDEG) erow[s] = 4*f + 2; }
        if (v.w != 0.0f) { int s = atomicAdd(&scnt, 1); if (s < MAXDEG) erow[s] = 4*f + 3; }
    }
    __syncthreads();
    if (threadIdx.x == 0) {
        int c = scnt;
        cnt[i] = (c < MAXDEG) ? c : MAXDEG;
        dinv[i] = rsqrtf(1.0f + (float)c);
    }
}

// ---------------------------------------------------------------------------
// prep_all: convert_x + prep_weights + ell-pad + zero-rows in ONE dispatch.
//   [0,CVX)     : xb = bf16(x)
//   [..+PW)     : w0t transpose; Mt = theta*W^T + (1-theta)*I fold
//   [..+PE)     : ell[i][e] = ZROW for e>=cnt[i]  (pads hit the zero row)
//   [..+ZR)     : zero row ZROW of h08/hP8/hQ8 (workspace is poisoned)
// ---------------------------------------------------------------------------
__global__ __launch_bounds__(256) void prep_all(const float* __restrict__ x,
                                                unsigned short* __restrict__ xb,
                                                const float* __restrict__ w0,
                                                const float* __restrict__ cw,
                                                unsigned short* __restrict__ w0t,
                                                unsigned short* __restrict__ Mt,
                                                int* __restrict__ ell,
                                                const int* __restrict__ cnt,
                                                unsigned int* __restrict__ h08,
                                                unsigned int* __restrict__ hP8,
                                                unsigned int* __restrict__ hQ8) {
    int b = blockIdx.x, t = threadIdx.x;
    if (b < CVX_BLOCKS) {
        int idx = b * 256 + t;
        float4 v = ((const float4*)x)[idx];
        ushort4v o;
        o.x = f2bf(v.x); o.y = f2bf(v.y); o.z = f2bf(v.z); o.w = f2bf(v.w);
        ((ushort4v*)xb)[idx] = o;
    } else if (b < CVX_BLOCKS + PW_BLOCKS) {
        int idx = (b - CVX_BLOCKS) * 256 + t;
        if (idx < 131072) {
            int n = idx >> 9, k = idx & 511;
            w0t[idx] = f2bf(w0[(size_t)k * 256 + n]);
        } else {
            int j = idx - 131072;
            int l = j >> 16;
            int r = j & 65535;
            int n = r >> 8, k = r & 255;
            float theta = logf(0.5f / (float)(l + 1) + 1.0f);
            float v = theta * cw[(size_t)l * 65536 + (size_t)k * 256 + n];
            if (k == n) v += 1.0f - theta;
            Mt[j] = f2bf(v);
        }
    } else if (b < CVX_BLOCKS + PW_BLOCKS + PE_BLOCKS) {
        int idx = (b - CVX_BLOCKS - PW_BLOCKS) * 256 + t;   // < 960000
        if (idx >= NN * MAXDEG) return;
        int i = idx / MAXDEG, e = idx % MAXDEG;
        if (e >= cnt[i]) ell[idx] = ZROW;                    // pad -> zero row
    } else {
        if (t < 64)        h08[(size_t)ZROW * 64 + t] = 0u;
        else if (t < 128)  hP8[(size_t)ZROW * 64 + (t - 64)] = 0u;
        else if (t < 192)  hQ8[(size_t)ZROW * 64 + (t - 128)] = 0u;
    }
}

// ---------------------------------------------------------------------------
// gemm0: h0 = relu(x @ w0 + b0); writes bf16 h0b AND PRE-SCALED fp8 h08:
//   h08[row] = fp8(16 * dinv[row] * h0[row])   (x16 = exact pow2 recenter,
//   keeps values in e4m3 prime range; undone by the layer's x1/16).
// ---------------------------------------------------------------------------
__global__ __launch_bounds__(512, 4) void gemm0_mfma(const unsigned short* __restrict__ xb,
                                                     const unsigned short* __restrict__ w0t,
                                                     const float* __restrict__ b0,
                                                     const float* __restrict__ dinv,
                                                     unsigned short* __restrict__ h0b,
                                                     unsigned char* __restrict__ h8o) {
    int t = threadIdx.x, wv = t >> 6, lane = t & 63;
    int lrow = lane & 15, quad = lane >> 4;
    int r0 = blockIdx.x * 16;

    bf16x8 a[16];
    const unsigned short* arow = xb + (size_t)(r0 + lrow) * NFEAT + quad * 8;
    #pragma unroll
    for (int f = 0; f < 16; ++f)
        a[f] = *(const bf16x8*)(arow + f * 32);

    #pragma unroll 1
    for (int n = 0; n < 2; ++n) {
        int nt = wv * 2 + n;
        floatx4 acc = {0.f, 0.f, 0.f, 0.f};
        const unsigned short* wrow = w0t + (size_t)(nt * 16 + lrow) * NFEAT + quad * 8;
        #pragma unroll
        for (int f = 0; f < 16; ++f) {
            bf16x8 bb = *(const bf16x8*)(wrow + f * 32);
            acc = __builtin_amdgcn_mfma_f32_16x16x32_bf16(a[f], bb, acc, 0, 0, 0);
        }
        int col = nt * 16 + lrow;
        float bias = b0[col];
        #pragma unroll
        for (int r = 0; r < 4; ++r) {
            int row = r0 + quad * 4 + r;
            unsigned short bv = f2bf(fmaxf(acc[r] + bias, 0.f));
            h0b[(size_t)row * NHID + col] = bv;
            h8o[(size_t)row * NHID + col] = f2fp8(bf2f(bv) * (16.0f * dinv[row]));
        }
    }
}

// ---------------------------------------------------------------------------
// gather helpers: 8-edge groups, VALUES-ONLY staging (scales pre-folded into
// h8) -> ping-pong = 32 VGPRs total, same budget as R7's 4-edge version but
// half the latency exposures.  R5's spill is structurally impossible.
// ---------------------------------------------------------------------------
__device__ __forceinline__ void load_g8(const int* __restrict__ e0r,
                                        const int* __restrict__ e1r,
                                        const unsigned int* __restrict__ h8,
                                        int lane, int base,
                                        unsigned int (&x0)[8], unsigned int (&x1)[8]) {
    #pragma unroll
    for (int u = 0; u < 8; ++u) {
        int j0 = e0r[base + u];            // uniform -> s_load
        int j1 = e1r[base + u];
        x0[u] = h8[(size_t)j0 * 64 + lane];
        x1[u] = h8[(size_t)j1 * 64 + lane];
    }
}

__device__ __forceinline__ void proc_g8(const unsigned int (&x0)[8],
                                        const unsigned int (&x1)[8],
                                        float4& a0, float4& a1) {
    #pragma unroll
    for (int u = 0; u < 8; ++u) {
        floatx2 lo = __builtin_amdgcn_cvt_pk_f32_fp8(x0[u], false);
        floatx2 hi = __builtin_amdgcn_cvt_pk_f32_fp8(x0[u], true);
        a0.x += lo.x; a0.y += lo.y; a0.z += hi.x; a0.w += hi.y;
        lo = __builtin_amdgcn_cvt_pk_f32_fp8(x1[u], false);
        hi = __builtin_amdgcn_cvt_pk_f32_fp8(x1[u], true);
        a1.x += lo.x; a1.y += lo.y; a1.z += hi.x; a1.w += hi.y;
    }
}

// ---------------------------------------------------------------------------
// layer_fused: block = 16 rows (grid 625), 8 waves; 2 rows/wave interleaved.
// Phase 1: pre-scaled fp8 gather (pure adds, no per-edge scale, no es array;
//          pads index the zero row).  acc self-init = cvt(h8'[i]) — self's
//          scale IS dinv[i], matching a_norm[i,i]=dinv^2 after the final
//          x(di/16).  Final: a *= 0.0625 (exact), then the unchanged
//          0.9*di*a + 0.1*h0 path.
// Phase 2: out = relu(sup @ M); non-last writes fp8(16*dinv[row]*out).
// LAST: logits + log_softmax in-block.
// ---------------------------------------------------------------------------
template<bool LAST>
__global__ __launch_bounds__(512, 6) void layer_fused(const unsigned int* __restrict__ h8,
                                                      const unsigned short* __restrict__ h0b,
                                                      const float* __restrict__ dinv,
                                                      const int* __restrict__ cnt,
                                                      const int* __restrict__ ell,
                                                      const unsigned short* __restrict__ Mt,
                                                      const float* __restrict__ w1,
                                                      const float* __restrict__ b1,
                                                      unsigned char* __restrict__ h8_out,
                                                      float* __restrict__ out) {
    __shared__ unsigned short supb[16][264];
    __shared__ float hs[LAST ? 16 * 264 : 4];
    __shared__ float sdi16[16];

    int t = threadIdx.x;
    int wv = __builtin_amdgcn_readfirstlane(t >> 6);
    int lane = t & 63;
    int r0 = blockIdx.x * 16;

    // ---- phase 1: pre-scaled fp8 gather -> supb ----
    int lr0 = wv * 2, lr1 = lr0 + 1;
    int i0 = r0 + lr0, i1 = r0 + lr1;

    unsigned int su0 = h8[(size_t)i0 * 64 + lane];
    unsigned int su1 = h8[(size_t)i1 * 64 + lane];
    ushort4v h0v0 = ((const ushort4v*)h0b)[(size_t)i0 * 64 + lane];
    ushort4v h0v1 = ((const ushort4v*)h0b)[(size_t)i1 * 64 + lane];

    float di0 = dinv[i0], di1 = dinv[i1];
    if (lane == 0) { sdi16[lr0] = 16.0f * di0; sdi16[lr1] = 16.0f * di1; }
    int dA = (cnt[i0] + 7) & ~7, dB = (cnt[i1] + 7) & ~7;
    int dm = dA > dB ? dA : dB;                 // pads -> zero row, add 0
    const int* e0r = ell + (size_t)i0 * MAXDEG;
    const int* e1r = ell + (size_t)i1 * MAXDEG;

    // self term: h8' already carries dinv_i (self scale IS dinv_i)
    floatx2 slo = __builtin_amdgcn_cvt_pk_f32_fp8(su0, false);
    floatx2 shi = __builtin_amdgcn_cvt_pk_f32_fp8(su0, true);
    float4 a0, a1;
    a0.x = slo.x; a0.y = slo.y; a0.z = shi.x; a0.w = shi.y;
    slo = __builtin_amdgcn_cvt_pk_f32_fp8(su1, false);
    shi = __builtin_amdgcn_cvt_pk_f32_fp8(su1, true);
    a1.x = slo.x; a1.y = slo.y; a1.z = shi.x; a1.w = shi.y;

    unsigned int xA0[8], xA1[8], xB0[8], xB1[8];
    int ng = dm >> 3;                           // 8-edge groups; 0 if isolated
    if (ng > 0) {
        load_g8(e0r, e1r, h8, lane, 0, xA0, xA1);
        bool useA = true;
        #pragma unroll 1
        for (int g = 1; g < ng; ++g) {
            if (useA) {
                load_g8(e0r, e1r, h8, lane, g << 3, xB0, xB1);
                proc_g8(xA0, xA1, a0, a1);
            } else {
                load_g8(e0r, e1r, h8, lane, g << 3, xA0, xA1);
                proc_g8(xB0, xB1, a0, a1);
            }
            useA = !useA;
        }
        if (useA) proc_g8(xA0, xA1, a0, a1);
        else      proc_g8(xB0, xB1, a0, a1);
    }

    // undo x16 (exact), then the unchanged mix path
    a0.x *= 0.0625f; a0.y *= 0.0625f; a0.z *= 0.0625f; a0.w *= 0.0625f;
    a1.x *= 0.0625f; a1.y *= 0.0625f; a1.z *= 0.0625f; a1.w *= 0.0625f;

    ushort4v ob;
    ob.x = f2bf(0.9f * (di0 * a0.x) + 0.1f * bf2f(h0v0.x));
    ob.y = f2bf(0.9f * (di0 * a0.y) + 0.1f * bf2f(h0v0.y));
    ob.z = f2bf(0.9f * (di0 * a0.z) + 0.1f * bf2f(h0v0.z));
    ob.w = f2bf(0.9f * (di0 * a0.w) + 0.1f * bf2f(h0v0.w));
    *(ushort4v*)&supb[lr0][4 * lane] = ob;
    ob.x = f2bf(0.9f * (di1 * a1.x) + 0.1f * bf2f(h0v1.x));
    ob.y = f2bf(0.9f * (di1 * a1.y) + 0.1f * bf2f(h0v1.y));
    ob.z = f2bf(0.9f * (di1 * a1.z) + 0.1f * bf2f(h0v1.z));
    ob.w = f2bf(0.9f * (di1 * a1.w) + 0.1f * bf2f(h0v1.w));
    *(ushort4v*)&supb[lr1][4 * lane] = ob;
    __syncthreads();

    // ---- phase 2: MFMA GEMM, epilogue = relu (+ pre-scale on fp8 write) ----
    int lrow = lane & 15, quad = lane >> 4;
    bf16x8 a[8];
    #pragma unroll
    for (int f = 0; f < 8; ++f)
        a[f] = *(const bf16x8*)&supb[lrow][quad * 8 + f * 32];

    #pragma unroll 1
    for (int n = 0; n < 2; ++n) {
        int nt = wv * 2 + n;
        floatx4 acc = {0.f, 0.f, 0.f, 0.f};
        const unsigned short* wrow = Mt + (size_t)(nt * 16 + lrow) * NHID + quad * 8;
        #pragma unroll
        for (int f = 0; f < 8; ++f) {
            bf16x8 bb = *(const bf16x8*)(wrow + f * 32);
            acc = __builtin_amdgcn_mfma_f32_16x16x32_bf16(a[f], bb, acc, 0, 0, 0);
        }
        int col = nt * 16 + lrow;
        #pragma unroll
        for (int r = 0; r < 4; ++r) {
            int lr2 = quad * 4 + r;
            float o = fmaxf(acc[r], 0.f);
            if (LAST) {
                hs[lr2 * 264 + col] = o;
            } else {
                h8_out[(size_t)(r0 + lr2) * NHID + col] = f2fp8(o * sdi16[lr2]);
            }
        }
    }

    // ---- phase 3 (LAST only): logits + log_softmax, in-block ----
    if (LAST) {
        __syncthreads();
        #pragma unroll 1
        for (int rr = 0; rr < 2; ++rr) {
            int lr = wv * 2 + rr;
            const float* hr = hs + lr * 264;
            float logit = -1e30f;
            if (lane < NCLASS) {
                float acc = b1[lane];
                #pragma unroll 8
                for (int k = 0; k < NHID; ++k)
                    acc = fmaf(hr[k], w1[k * NCLASS + lane], acc);
                logit = acc;
            }
            float m = logit;
            #pragma unroll
            for (int off = 32; off > 0; off >>= 1)
                m = fmaxf(m, __shfl_xor(m, off, 64));
            float e = (lane < NCLASS) ? expf(logit - m) : 0.0f;
            float ssum = e;
            #pragma unroll
            for (int off = 32; off > 0; off >>= 1)
                ssum += __shfl_xor(ssum, off, 64);
            float lse = m + logf(ssum);
            if (lane < NCLASS)
                out[(size_t)(r0 + lr) * NCLASS + lane] = logit - lse;
        }
    }
}

// ---------------------------------------------------------------------------
extern "C" void kernel_launch(void* const* d_in, const int* in_sizes, int n_in,
                              void* d_out, int out_size, void* d_ws, size_t ws_size,
                              hipStream_t stream) {
    const float* x      = (const float*)d_in[0];
    const float* adj    = (const float*)d_in[1];
    const float* w0     = (const float*)d_in[2];
    const float* b0     = (const float*)d_in[3];
    const float* conv_w = (const float*)d_in[4];
    const float* w1     = (const float*)d_in[5];
    const float* b1     = (const float*)d_in[6];
    float* out = (float*)d_out;

    char* ws = (char*)d_ws;
    size_t off = 0;
    auto alloc = [&](size_t bytes) -> void* {
        void* p = ws + off;
        off = (off + bytes + 255) & ~(size_t)255;
        return p;
    };
    float*          dinv  = (float*)alloc((size_t)NN * 4);
    int*            cnt   = (int*)  alloc((size_t)NN * 4);
    int*            ell   = (int*)  alloc((size_t)NN * MAXDEG * 4);
    unsigned short* xb    = (unsigned short*)alloc((size_t)NN * NFEAT * 2);
    unsigned short* w0t   = (unsigned short*)alloc((size_t)NFEAT * NHID * 2);
    unsigned short* Mt    = (unsigned short*)alloc((size_t)NLAYERS * NHID * NHID * 2);
    unsigned short* h0b   = (unsigned short*)alloc((size_t)NN * NHID * 2);
    unsigned int*   h08   = (unsigned int*)alloc((size_t)(NN + 1) * NHID);  // +zero row
    unsigned int*   hP8   = (unsigned int*)alloc((size_t)(NN + 1) * NHID);
    unsigned int*   hQ8   = (unsigned int*)alloc((size_t)(NN + 1) * NHID);

    build_graph<<<NN, 256, 0, stream>>>(adj, cnt, ell, dinv);
    prep_all<<<CVX_BLOCKS + PW_BLOCKS + PE_BLOCKS + ZR_BLOCKS, 256, 0, stream>>>(
        x, xb, w0, conv_w, w0t, Mt, ell, cnt, h08, hP8, hQ8);
    gemm0_mfma<<<NN / 16, 512, 0, stream>>>(xb, w0t, b0, dinv, h0b, (unsigned char*)h08);

    const unsigned int* hc8 = h08;
    for (int l = 0; l < NLAYERS; ++l) {
        unsigned int* nxt = (l & 1) ? hQ8 : hP8;
        const unsigned short* wt = Mt + (size_t)l * NHID * NHID;
        if (l == NLAYERS - 1)
            layer_fused<true><<<NN / 16, 512, 0, stream>>>(hc8, h0b, dinv, cnt, ell, wt, w1, b1, nullptr, out);
        else
            layer_fused<false><<<NN / 16, 512, 0, stream>>>(hc8, h0b, dinv, cnt, ell, wt, nullptr, nullptr, (unsigned char*)nxt, nullptr);
        hc8 = nxt;
    }
}

// Round 12
// 804.634 us; speedup vs baseline: 1.2227x; 1.1073x over previous
//
#include <hip/hip_runtime.h>
#include <math.h>

#define NN 10000
#define NFEAT 512
#define NHID 256
#define NCLASS 40
#define NLAYERS 8
#define MAXDEG 96

#define CVX_BLOCKS 5000   // convert_x   : 1,280,000 float4 / 256
#define PW_BLOCKS  2560   // prep_weights:   655,360 idx   / 256
#define PE_BLOCKS  3750   // prep_ell    :   960,000 idx   / 256

typedef __attribute__((ext_vector_type(8))) short bf16x8;
typedef __attribute__((ext_vector_type(4))) float floatx4;
typedef __attribute__((ext_vector_type(2))) float floatx2;
typedef __attribute__((ext_vector_type(4))) unsigned short ushort4v;
typedef __attribute__((ext_vector_type(8))) unsigned short ushort8v;

__device__ __forceinline__ unsigned short f2bf(float f) {
    union { float f; unsigned int u; } v; v.f = f;
    unsigned int r = v.u + 0x7fffu + ((v.u >> 16) & 1u);  // RNE
    return (unsigned short)(r >> 16);
}
__device__ __forceinline__ float bf2f(unsigned short h) {
    union { unsigned int u; float f; } v; v.u = ((unsigned int)h) << 16;
    return v.f;
}
__device__ __forceinline__ unsigned char f2fp8(float f) {
    return (unsigned char)(__builtin_amdgcn_cvt_pk_fp8_f32(f, f, 0, false) & 0xFF);
}

// ---------------------------------------------------------------------------
// build_graph: one block per row; one pass over the 400MB dense adjacency.
// HBM-bound floor ~63us — irreducible.
// ---------------------------------------------------------------------------
__global__ __launch_bounds__(256) void build_graph(const float* __restrict__ adj,
                                                   int* __restrict__ cnt,
                                                   int* __restrict__ ell,
                                                   float* __restrict__ dinv) {
    int i = blockIdx.x;
    __shared__ int scnt;
    if (threadIdx.x == 0) scnt = 0;
    __syncthreads();
    const float4* row = (const float4*)(adj + (size_t)i * NN);
    int* erow = ell + (size_t)i * MAXDEG;
    for (int f = threadIdx.x; f < NN / 4; f += 256) {
        float4 v = row[f];
        if (v.x != 0.0f) { int s = atomicAdd(&scnt, 1); if (s < MAXDEG) erow[s] = 4*f + 0; }
        if (v.y != 0.0f) { int s = atomicAdd(&scnt, 1); if (s < MAXDEG) erow[s] = 4*f + 1; }
        if (v.z != 0.0f) { int s = atomicAdd(&scnt, 1); if (s < MAXDEG) erow[s] = 4*f + 2; }
        if (v.w != 0.0f) { int s = atomicAdd(&scnt, 1); if (s < MAXDEG) erow[s] = 4*f + 3; }
    }
    __syncthreads();
    if (threadIdx.x == 0) {
        int c = scnt;
        cnt[i] = (c < MAXDEG) ? c : MAXDEG;
        dinv[i] = rsqrtf(1.0f + (float)c);
    }
}

// ---------------------------------------------------------------------------
// prep_all: convert_x + prep_weights + prep_ell merged (R7 structure).
// ---------------------------------------------------------------------------
__global__ __launch_bounds__(256) void prep_all(const float* __restrict__ x,
                                                unsigned short* __restrict__ xb,
                                                const float* __restrict__ w0,
                                                const float* __restrict__ cw,
                                                unsigned short* __restrict__ w0t,
                                                unsigned short* __restrict__ Mt,
                                                const int* __restrict__ ell,
                                                const int* __restrict__ cnt,
                                                const float* __restrict__ dinv,
                                                int2* __restrict__ es) {
    int b = blockIdx.x, t = threadIdx.x;
    if (b < CVX_BLOCKS) {
        int idx = b * 256 + t;
        float4 v = ((const float4*)x)[idx];
        ushort4v o;
        o.x = f2bf(v.x); o.y = f2bf(v.y); o.z = f2bf(v.z); o.w = f2bf(v.w);
        ((ushort4v*)xb)[idx] = o;
    } else if (b < CVX_BLOCKS + PW_BLOCKS) {
        int idx = (b - CVX_BLOCKS) * 256 + t;
        if (idx < 131072) {
            int n = idx >> 9, k = idx & 511;
            w0t[idx] = f2bf(w0[(size_t)k * 256 + n]);
        } else {
            int j = idx - 131072;
            int l = j >> 16;
            int r = j & 65535;
            int n = r >> 8, k = r & 255;
            float theta = logf(0.5f / (float)(l + 1) + 1.0f);
            float v = theta * cw[(size_t)l * 65536 + (size_t)k * 256 + n];
            if (k == n) v += 1.0f - theta;
            Mt[j] = f2bf(v);
        }
    } else {
        int idx = (b - CVX_BLOCKS - PW_BLOCKS) * 256 + t;   // < 960000
        if (idx >= NN * MAXDEG) return;
        int i = idx / MAXDEG, e = idx % MAXDEG;
        int2 v; v.x = 0; v.y = 0;                            // pad: row 0, x0.0
        if (e < cnt[i]) {
            int j = ell[idx];
            v.x = j; v.y = __float_as_int(dinv[j]);
        }
        es[idx] = v;
    }
}

// ---------------------------------------------------------------------------
// gemm0: h0 = relu(x @ w0 + b0); bf16 h0b AND fp8 h08 (fused convert).
// ---------------------------------------------------------------------------
__global__ __launch_bounds__(512, 4) void gemm0_mfma(const unsigned short* __restrict__ xb,
                                                     const unsigned short* __restrict__ w0t,
                                                     const float* __restrict__ b0,
                                                     unsigned short* __restrict__ h0b,
                                                     unsigned char* __restrict__ h8o) {
    int t = threadIdx.x, wv = t >> 6, lane = t & 63;
    int lrow = lane & 15, quad = lane >> 4;
    int r0 = blockIdx.x * 16;

    bf16x8 a[16];
    const unsigned short* arow = xb + (size_t)(r0 + lrow) * NFEAT + quad * 8;
    #pragma unroll
    for (int f = 0; f < 16; ++f)
        a[f] = *(const bf16x8*)(arow + f * 32);

    #pragma unroll 1
    for (int n = 0; n < 2; ++n) {
        int nt = wv * 2 + n;
        floatx4 acc = {0.f, 0.f, 0.f, 0.f};
        const unsigned short* wrow = w0t + (size_t)(nt * 16 + lrow) * NFEAT + quad * 8;
        #pragma unroll
        for (int f = 0; f < 16; ++f) {
            bf16x8 bb = *(const bf16x8*)(wrow + f * 32);
            acc = __builtin_amdgcn_mfma_f32_16x16x32_bf16(a[f], bb, acc, 0, 0, 0);
        }
        int col = nt * 16 + lrow;
        float bias = b0[col];
        #pragma unroll
        for (int r = 0; r < 4; ++r) {
            int row = r0 + quad * 4 + r;
            unsigned short bv = f2bf(fmaxf(acc[r] + bias, 0.f));
            h0b[(size_t)row * NHID + col] = bv;
            h8o[(size_t)row * NHID + col] = f2fp8(bf2f(bv));
        }
    }
}

// ---------------------------------------------------------------------------
// paired-lane gather helpers: one dwordx2 load covers HALF a row per lane,
// so a full wave (64 lanes) fetches TWO edges per load instruction:
//   lanes 0-31  -> edge base+2k   (even chain)
//   lanes 32-63 -> edge base+2k+1 (odd chain)
// Group = 4 edges/row = 2 paired loads/row = 4 load issues per 2 rows
// (R7 needed 8).  Staging per ping-pong buffer: 2 uint2 + 2 scales per row
// = 12 VGPR; x2 buffers = 24.  Acc = 16.  Total ~72 < 85 cap: no spill.
// ---------------------------------------------------------------------------
__device__ __forceinline__ void load_pg(const int2* __restrict__ e0r,
                                        const int2* __restrict__ e1r,
                                        const unsigned int* __restrict__ h8,
                                        int half, int hl, int base,
                                        uint2 (&x0)[2], uint2 (&x1)[2],
                                        float (&s0)[2], float (&s1)[2]) {
    #pragma unroll
    for (int k = 0; k < 2; ++k) {
        int2 pA = e0r[base + 2 * k];            // uniform -> s_load
        int2 pB = e0r[base + 2 * k + 1];
        int  j0 = half ? pB.x : pA.x;           // v_cndmask
        s0[k] = __int_as_float(half ? pB.y : pA.y);
        x0[k] = *(const uint2*)(h8 + (size_t)j0 * 64 + 2 * hl);
        int2 qA = e1r[base + 2 * k];
        int2 qB = e1r[base + 2 * k + 1];
        int  j1 = half ? qB.x : qA.x;
        s1[k] = __int_as_float(half ? qB.y : qA.y);
        x1[k] = *(const uint2*)(h8 + (size_t)j1 * 64 + 2 * hl);
    }
}

__device__ __forceinline__ void proc_pg(const uint2 (&x0)[2], const uint2 (&x1)[2],
                                        const float (&s0)[2], const float (&s1)[2],
                                        float4& aA0, float4& aB0,
                                        float4& aA1, float4& aB1) {
    #pragma unroll
    for (int k = 0; k < 2; ++k) {
        floatx2 lo = __builtin_amdgcn_cvt_pk_f32_fp8(x0[k].x, false);
        floatx2 hi = __builtin_amdgcn_cvt_pk_f32_fp8(x0[k].x, true);
        aA0.x = fmaf(s0[k], lo.x, aA0.x);
        aA0.y = fmaf(s0[k], lo.y, aA0.y);
        aA0.z = fmaf(s0[k], hi.x, aA0.z);
        aA0.w = fmaf(s0[k], hi.y, aA0.w);
        lo = __builtin_amdgcn_cvt_pk_f32_fp8(x0[k].y, false);
        hi = __builtin_amdgcn_cvt_pk_f32_fp8(x0[k].y, true);
        aB0.x = fmaf(s0[k], lo.x, aB0.x);
        aB0.y = fmaf(s0[k], lo.y, aB0.y);
        aB0.z = fmaf(s0[k], hi.x, aB0.z);
        aB0.w = fmaf(s0[k], hi.y, aB0.w);
        lo = __builtin_amdgcn_cvt_pk_f32_fp8(x1[k].x, false);
        hi = __builtin_amdgcn_cvt_pk_f32_fp8(x1[k].x, true);
        aA1.x = fmaf(s1[k], lo.x, aA1.x);
        aA1.y = fmaf(s1[k], lo.y, aA1.y);
        aA1.z = fmaf(s1[k], hi.x, aA1.z);
        aA1.w = fmaf(s1[k], hi.y, aA1.w);
        lo = __builtin_amdgcn_cvt_pk_f32_fp8(x1[k].y, false);
        hi = __builtin_amdgcn_cvt_pk_f32_fp8(x1[k].y, true);
        aB1.x = fmaf(s1[k], lo.x, aB1.x);
        aB1.y = fmaf(s1[k], lo.y, aB1.y);
        aB1.z = fmaf(s1[k], hi.x, aB1.z);
        aB1.w = fmaf(s1[k], hi.y, aB1.w);
    }
}

__device__ __forceinline__ float4 half_sum(float4 v, int src) {
    v.x += __shfl(v.x, src, 64);
    v.y += __shfl(v.y, src, 64);
    v.z += __shfl(v.z, src, 64);
    v.w += __shfl(v.w, src, 64);
    return v;
}

// ---------------------------------------------------------------------------
// layer_fused: block = 16 rows (grid 625), 8 waves; 2 rows/wave.
// Phase 1: paired-lane dwordx2 gather (2 edges per load instruction) with
//          R7's 4-edge ping-pong pipeline.  Even/odd chains accumulate in
//          lane halves; combined via __shfl; self applied after combine:
//          sum = fma(di, self, even+odd).  fp32 reorder only (R9-class,
//          5x threshold headroom).  Per-value rounding path unchanged.
// Phase 2: out = relu(sup @ M), M pre-folded.  LAST: logits + log_softmax.
// ---------------------------------------------------------------------------
template<bool LAST>
__global__ __launch_bounds__(512, 6) void layer_fused(const unsigned int* __restrict__ h8,
                                                      const unsigned short* __restrict__ h0b,
                                                      const float* __restrict__ dinv,
                                                      const int* __restrict__ cnt,
                                                      const int2* __restrict__ es,
                                                      const unsigned short* __restrict__ Mt,
                                                      const float* __restrict__ w1,
                                                      const float* __restrict__ b1,
                                                      unsigned char* __restrict__ h8_out,
                                                      float* __restrict__ out) {
    __shared__ unsigned short supb[16][264];
    __shared__ float hs[LAST ? 16 * 264 : 4];

    int t = threadIdx.x;
    int wv = __builtin_amdgcn_readfirstlane(t >> 6);
    int lane = t & 63;
    int half = lane >> 5, hl = lane & 31;
    int r0 = blockIdx.x * 16;

    // ---- phase 1: paired-lane pipelined gather -> supb ----
    int lr0 = wv * 2, lr1 = lr0 + 1;
    int i0 = r0 + lr0, i1 = r0 + lr1;

    // self pairs + h0 residual (lane hl covers cols 8hl..8hl+7; low half used)
    uint2 su0 = *(const uint2*)(h8 + (size_t)i0 * 64 + 2 * hl);
    uint2 su1 = *(const uint2*)(h8 + (size_t)i1 * 64 + 2 * hl);
    ushort8v h0v0 = *(const ushort8v*)(h0b + (size_t)i0 * NHID + 8 * hl);
    ushort8v h0v1 = *(const ushort8v*)(h0b + (size_t)i1 * NHID + 8 * hl);

    float di0 = dinv[i0], di1 = dinv[i1];
    int dA = (cnt[i0] + 7) & ~7, dB = (cnt[i1] + 7) & ~7;
    int dm = dA > dB ? dA : dB;                 // pads are x0.0, safe
    const int2* e0r = es + (size_t)i0 * MAXDEG;
    const int2* e1r = es + (size_t)i1 * MAXDEG;

    float4 aA0 = {0.f,0.f,0.f,0.f}, aB0 = {0.f,0.f,0.f,0.f};
    float4 aA1 = {0.f,0.f,0.f,0.f}, aB1 = {0.f,0.f,0.f,0.f};

    uint2 xA0[2], xA1[2], xB0[2], xB1[2];
    float sA0[2], sA1[2], sB0[2], sB1[2];
    int nh = dm >> 2;                           // 4-edge groups (even count)
    if (nh > 0) {
        load_pg(e0r, e1r, h8, half, hl, 0, xA0, xA1, sA0, sA1);
        bool useA = true;
        #pragma unroll 1
        for (int g = 1; g < nh; ++g) {
            if (useA) {
                load_pg(e0r, e1r, h8, half, hl, g << 2, xB0, xB1, sB0, sB1);
                proc_pg(xA0, xA1, sA0, sA1, aA0, aB0, aA1, aB1);
            } else {
                load_pg(e0r, e1r, h8, half, hl, g << 2, xA0, xA1, sA0, sA1);
                proc_pg(xB0, xB1, sB0, sB1, aA0, aB0, aA1, aB1);
            }
            useA = !useA;
        }
        if (useA) proc_pg(xA0, xA1, sA0, sA1, aA0, aB0, aA1, aB1);
        else      proc_pg(xB0, xB1, sB0, sB1, aA0, aB0, aA1, aB1);
    }

    // combine even (low-half) + odd (high-half) chains; valid on lanes < 32
    int src = hl | 32;
    aA0 = half_sum(aA0, src); aB0 = half_sum(aB0, src);
    aA1 = half_sum(aA1, src); aB1 = half_sum(aB1, src);

    // self + mix + write (lanes 0-31 hold the full row)
    {
        floatx2 lo = __builtin_amdgcn_cvt_pk_f32_fp8(su0.x, false);
        floatx2 hi = __builtin_amdgcn_cvt_pk_f32_fp8(su0.x, true);
        float4 vA; float4 vB;
        vA.x = fmaf(di0, lo.x, aA0.x); vA.y = fmaf(di0, lo.y, aA0.y);
        vA.z = fmaf(di0, hi.x, aA0.z); vA.w = fmaf(di0, hi.y, aA0.w);
        lo = __builtin_amdgcn_cvt_pk_f32_fp8(su0.y, false);
        hi = __builtin_amdgcn_cvt_pk_f32_fp8(su0.y, true);
        vB.x = fmaf(di0, lo.x, aB0.x); vB.y = fmaf(di0, lo.y, aB0.y);
        vB.z = fmaf(di0, hi.x, aB0.z); vB.w = fmaf(di0, hi.y, aB0.w);
        ushort8v ob;
        ob[0] = f2bf(0.9f * (di0 * vA.x) + 0.1f * bf2f(h0v0[0]));
        ob[1] = f2bf(0.9f * (di0 * vA.y) + 0.1f * bf2f(h0v0[1]));
        ob[2] = f2bf(0.9f * (di0 * vA.z) + 0.1f * bf2f(h0v0[2]));
        ob[3] = f2bf(0.9f * (di0 * vA.w) + 0.1f * bf2f(h0v0[3]));
        ob[4] = f2bf(0.9f * (di0 * vB.x) + 0.1f * bf2f(h0v0[4]));
        ob[5] = f2bf(0.9f * (di0 * vB.y) + 0.1f * bf2f(h0v0[5]));
        ob[6] = f2bf(0.9f * (di0 * vB.z) + 0.1f * bf2f(h0v0[6]));
        ob[7] = f2bf(0.9f * (di0 * vB.w) + 0.1f * bf2f(h0v0[7]));
        if (lane < 32) *(ushort8v*)&supb[lr0][8 * hl] = ob;
    }
    {
        floatx2 lo = __builtin_amdgcn_cvt_pk_f32_fp8(su1.x, false);
        floatx2 hi = __builtin_amdgcn_cvt_pk_f32_fp8(su1.x, true);
        float4 vA; float4 vB;
        vA.x = fmaf(di1, lo.x, aA1.x); vA.y = fmaf(di1, lo.y, aA1.y);
        vA.z = fmaf(di1, hi.x, aA1.z); vA.w = fmaf(di1, hi.y, aA1.w);
        lo = __builtin_amdgcn_cvt_pk_f32_fp8(su1.y, false);
        hi = __builtin_amdgcn_cvt_pk_f32_fp8(su1.y, true);
        vB.x = fmaf(di1, lo.x, aB1.x); vB.y = fmaf(di1, lo.y, aB1.y);
        vB.z = fmaf(di1, hi.x, aB1.z); vB.w = fmaf(di1, hi.y, aB1.w);
        ushort8v ob;
        ob[0] = f2bf(0.9f * (di1 * vA.x) + 0.1f * bf2f(h0v1[0]));
        ob[1] = f2bf(0.9f * (di1 * vA.y) + 0.1f * bf2f(h0v1[1]));
        ob[2] = f2bf(0.9f * (di1 * vA.z) + 0.1f * bf2f(h0v1[2]));
        ob[3] = f2bf(0.9f * (di1 * vA.w) + 0.1f * bf2f(h0v1[3]));
        ob[4] = f2bf(0.9f * (di1 * vB.x) + 0.1f * bf2f(h0v1[4]));
        ob[5] = f2bf(0.9f * (di1 * vB.y) + 0.1f * bf2f(h0v1[5]));
        ob[6] = f2bf(0.9f * (di1 * vB.z) + 0.1f * bf2f(h0v1[6]));
        ob[7] = f2bf(0.9f * (di1 * vB.w) + 0.1f * bf2f(h0v1[7]));
        if (lane < 32) *(ushort8v*)&supb[lr1][8 * hl] = ob;
    }
    __syncthreads();

    // ---- phase 2: MFMA GEMM (residual folded in M) ----
    int lrow = lane & 15, quad = lane >> 4;
    bf16x8 a[8];
    #pragma unroll
    for (int f = 0; f < 8; ++f)
        a[f] = *(const bf16x8*)&supb[lrow][quad * 8 + f * 32];

    #pragma unroll 1
    for (int n = 0; n < 2; ++n) {
        int nt = wv * 2 + n;
        floatx4 acc = {0.f, 0.f, 0.f, 0.f};
        const unsigned short* wrow = Mt + (size_t)(nt * 16 + lrow) * NHID + quad * 8;
        #pragma unroll
        for (int f = 0; f < 8; ++f) {
            bf16x8 bb = *(const bf16x8*)(wrow + f * 32);
            acc = __builtin_amdgcn_mfma_f32_16x16x32_bf16(a[f], bb, acc, 0, 0, 0);
        }
        int col = nt * 16 + lrow;
        #pragma unroll
        for (int r = 0; r < 4; ++r) {
            int lr2 = quad * 4 + r;
            float o = fmaxf(acc[r], 0.f);
            if (LAST) {
                hs[lr2 * 264 + col] = o;
            } else {
                h8_out[(size_t)(r0 + lr2) * NHID + col] = f2fp8(o);
            }
        }
    }

    // ---- phase 3 (LAST only): logits + log_softmax ----
    if (LAST) {
        __syncthreads();
        #pragma unroll 1
        for (int rr = 0; rr < 2; ++rr) {
            int lr = wv * 2 + rr;
            const float* hr = hs + lr * 264;
            float logit = -1e30f;
            if (lane < NCLASS) {
                float acc = b1[lane];
                #pragma unroll 8
                for (int k = 0; k < NHID; ++k)
                    acc = fmaf(hr[k], w1[k * NCLASS + lane], acc);
                logit = acc;
            }
            float m = logit;
            #pragma unroll
            for (int off = 32; off > 0; off >>= 1)
                m = fmaxf(m, __shfl_xor(m, off, 64));
            float e = (lane < NCLASS) ? expf(logit - m) : 0.0f;
            float ssum = e;
            #pragma unroll
            for (int off = 32; off > 0; off >>= 1)
                ssum += __shfl_xor(ssum, off, 64);
            float lse = m + logf(ssum);
            if (lane < NCLASS)
                out[(size_t)(r0 + lr) * NCLASS + lane] = logit - lse;
        }
    }
}

// ---------------------------------------------------------------------------
extern "C" void kernel_launch(void* const* d_in, const int* in_sizes, int n_in,
                              void* d_out, int out_size, void* d_ws, size_t ws_size,
                              hipStream_t stream) {
    const float* x      = (const float*)d_in[0];
    const float* adj    = (const float*)d_in[1];
    const float* w0     = (const float*)d_in[2];
    const float* b0     = (const float*)d_in[3];
    const float* conv_w = (const float*)d_in[4];
    const float* w1     = (const float*)d_in[5];
    const float* b1     = (const float*)d_in[6];
    float* out = (float*)d_out;

    char* ws = (char*)d_ws;
    size_t off = 0;
    auto alloc = [&](size_t bytes) -> void* {
        void* p = ws + off;
        off = (off + bytes + 255) & ~(size_t)255;
        return p;
    };
    float*          dinv  = (float*)alloc((size_t)NN * 4);
    int*            cnt   = (int*)  alloc((size_t)NN * 4);
    int*            ell   = (int*)  alloc((size_t)NN * MAXDEG * 4);
    int2*           es    = (int2*) alloc((size_t)NN * MAXDEG * 8);
    unsigned short* xb    = (unsigned short*)alloc((size_t)NN * NFEAT * 2);
    unsigned short* w0t   = (unsigned short*)alloc((size_t)NFEAT * NHID * 2);
    unsigned short* Mt    = (unsigned short*)alloc((size_t)NLAYERS * NHID * NHID * 2);
    unsigned short* h0b   = (unsigned short*)alloc((size_t)NN * NHID * 2);
    unsigned int*   h08   = (unsigned int*)alloc((size_t)NN * NHID);
    unsigned int*   hP8   = (unsigned int*)alloc((size_t)NN * NHID);
    unsigned int*   hQ8   = (unsigned int*)alloc((size_t)NN * NHID);

    build_graph<<<NN, 256, 0, stream>>>(adj, cnt, ell, dinv);
    prep_all<<<CVX_BLOCKS + PW_BLOCKS + PE_BLOCKS, 256, 0, stream>>>(
        x, xb, w0, conv_w, w0t, Mt, ell, cnt, dinv, es);
    gemm0_mfma<<<NN / 16, 512, 0, stream>>>(xb, w0t, b0, h0b, (unsigned char*)h08);

    const unsigned int* hc8 = h08;
    for (int l = 0; l < NLAYERS; ++l) {
        unsigned int* nxt = (l & 1) ? hQ8 : hP8;
        const unsigned short* wt = Mt + (size_t)l * NHID * NHID;
        if (l == NLAYERS - 1)
            layer_fused<true><<<NN / 16, 512, 0, stream>>>(hc8, h0b, dinv, cnt, es, wt, w1, b1, nullptr, out);
        else
            layer_fused<false><<<NN / 16, 512, 0, stream>>>(hc8, h0b, dinv, cnt, es, wt, nullptr, nullptr, (unsigned char*)nxt, nullptr);
        hc8 = nxt;
    }
}

// Round 13
// 789.271 us; speedup vs baseline: 1.2465x; 1.0195x over previous
//
#include <hip/hip_runtime.h>
#include <math.h>

#define NN 10000
#define NFEAT 512
#define NHID 256
#define NCLASS 40
#define NLAYERS 8
#define MAXDEG 96

#define CVX_BLOCKS 5000   // convert_x   : 1,280,000 float4 / 256
#define PW_BLOCKS  2560   // prep_weights:   655,360 idx   / 256
#define PE_BLOCKS  3750   // prep_ell    :   960,000 idx   / 256

typedef __attribute__((ext_vector_type(8))) short bf16x8;
typedef __attribute__((ext_vector_type(4))) float floatx4;
typedef __attribute__((ext_vector_type(2))) float floatx2;
typedef __attribute__((ext_vector_type(4))) unsigned short ushort4v;

__device__ __forceinline__ unsigned short f2bf(float f) {
    union { float f; unsigned int u; } v; v.f = f;
    unsigned int r = v.u + 0x7fffu + ((v.u >> 16) & 1u);  // RNE
    return (unsigned short)(r >> 16);
}
__device__ __forceinline__ float bf2f(unsigned short h) {
    union { unsigned int u; float f; } v; v.u = ((unsigned int)h) << 16;
    return v.f;
}
__device__ __forceinline__ unsigned char f2fp8(float f) {
    return (unsigned char)(__builtin_amdgcn_cvt_pk_fp8_f32(f, f, 0, false) & 0xFF);
}

// ---------------------------------------------------------------------------
// build_graph: one block per row; one pass over the 400MB dense adjacency.
// HBM-bound floor ~63us — irreducible.
// ---------------------------------------------------------------------------
__global__ __launch_bounds__(256) void build_graph(const float* __restrict__ adj,
                                                   int* __restrict__ cnt,
                                                   int* __restrict__ ell,
                                                   float* __restrict__ dinv) {
    int i = blockIdx.x;
    __shared__ int scnt;
    if (threadIdx.x == 0) scnt = 0;
    __syncthreads();
    const float4* row = (const float4*)(adj + (size_t)i * NN);
    int* erow = ell + (size_t)i * MAXDEG;
    for (int f = threadIdx.x; f < NN / 4; f += 256) {
        float4 v = row[f];
        if (v.x != 0.0f) { int s = atomicAdd(&scnt, 1); if (s < MAXDEG) erow[s] = 4*f + 0; }
        if (v.y != 0.0f) { int s = atomicAdd(&scnt, 1); if (s < MAXDEG) erow[s] = 4*f + 1; }
        if (v.z != 0.0f) { int s = atomicAdd(&scnt, 1); if (s < MAXDEG) erow[s] = 4*f + 2; }
        if (v.w != 0.0f) { int s = atomicAdd(&scnt, 1); if (s < MAXDEG) erow[s] = 4*f + 3; }
    }
    __syncthreads();
    if (threadIdx.x == 0) {
        int c = scnt;
        cnt[i] = (c < MAXDEG) ? c : MAXDEG;
        dinv[i] = rsqrtf(1.0f + (float)c);
    }
}

// ---------------------------------------------------------------------------
// prep_all: convert_x + prep_weights + prep_ell merged (blockIdx-range split;
// the three are mutually independent, all only need build_graph's outputs).
//   [0, CVX)            : xb = bf16(x)
//   [CVX, CVX+PW)       : w0t/Mt transposes + residual fold
//   [CVX+PW, +PE)       : es[i][e] = (j, bits(dinv[j])) | (0, 0.0) pad
// ---------------------------------------------------------------------------
__global__ __launch_bounds__(256) void prep_all(const float* __restrict__ x,
                                                unsigned short* __restrict__ xb,
                                                const float* __restrict__ w0,
                                                const float* __restrict__ cw,
                                                unsigned short* __restrict__ w0t,
                                                unsigned short* __restrict__ Mt,
                                                const int* __restrict__ ell,
                                                const int* __restrict__ cnt,
                                                const float* __restrict__ dinv,
                                                int2* __restrict__ es) {
    int b = blockIdx.x, t = threadIdx.x;
    if (b < CVX_BLOCKS) {
        int idx = b * 256 + t;
        float4 v = ((const float4*)x)[idx];
        ushort4v o;
        o.x = f2bf(v.x); o.y = f2bf(v.y); o.z = f2bf(v.z); o.w = f2bf(v.w);
        ((ushort4v*)xb)[idx] = o;
    } else if (b < CVX_BLOCKS + PW_BLOCKS) {
        int idx = (b - CVX_BLOCKS) * 256 + t;
        if (idx < 131072) {
            int n = idx >> 9, k = idx & 511;
            w0t[idx] = f2bf(w0[(size_t)k * 256 + n]);
        } else {
            int j = idx - 131072;
            int l = j >> 16;
            int r = j & 65535;
            int n = r >> 8, k = r & 255;
            float theta = logf(0.5f / (float)(l + 1) + 1.0f);
            float v = theta * cw[(size_t)l * 65536 + (size_t)k * 256 + n];
            if (k == n) v += 1.0f - theta;
            Mt[j] = f2bf(v);
        }
    } else {
        int idx = (b - CVX_BLOCKS - PW_BLOCKS) * 256 + t;   // < 960000
        if (idx >= NN * MAXDEG) return;
        int i = idx / MAXDEG, e = idx % MAXDEG;
        int2 v; v.x = 0; v.y = 0;                            // pad: row 0, x0.0
        if (e < cnt[i]) {
            int j = ell[idx];
            v.x = j; v.y = __float_as_int(dinv[j]);
        }
        es[idx] = v;
    }
}

// ---------------------------------------------------------------------------
// gemm0: h0 = relu(x @ w0 + b0); writes bf16 h0b AND fp8 h08 (convert fused,
// numerically identical: fp8 encoded from the rounded bf16 value).
// ---------------------------------------------------------------------------
__global__ __launch_bounds__(512, 4) void gemm0_mfma(const unsigned short* __restrict__ xb,
                                                     const unsigned short* __restrict__ w0t,
                                                     const float* __restrict__ b0,
                                                     unsigned short* __restrict__ h0b,
                                                     unsigned char* __restrict__ h8o) {
    int t = threadIdx.x, wv = t >> 6, lane = t & 63;
    int lrow = lane & 15, quad = lane >> 4;
    int r0 = blockIdx.x * 16;

    bf16x8 a[16];
    const unsigned short* arow = xb + (size_t)(r0 + lrow) * NFEAT + quad * 8;
    #pragma unroll
    for (int f = 0; f < 16; ++f)
        a[f] = *(const bf16x8*)(arow + f * 32);

    #pragma unroll 1
    for (int n = 0; n < 2; ++n) {
        int nt = wv * 2 + n;
        floatx4 acc = {0.f, 0.f, 0.f, 0.f};
        const unsigned short* wrow = w0t + (size_t)(nt * 16 + lrow) * NFEAT + quad * 8;
        #pragma unroll
        for (int f = 0; f < 16; ++f) {
            bf16x8 bb = *(const bf16x8*)(wrow + f * 32);
            acc = __builtin_amdgcn_mfma_f32_16x16x32_bf16(a[f], bb, acc, 0, 0, 0);
        }
        int col = nt * 16 + lrow;
        float bias = b0[col];
        #pragma unroll
        for (int r = 0; r < 4; ++r) {
            int row = r0 + quad * 4 + r;
            unsigned short bv = f2bf(fmaxf(acc[r] + bias, 0.f));
            h0b[(size_t)row * NHID + col] = bv;
            h8o[(size_t)row * NHID + col] = f2fp8(bf2f(bv));
        }
    }
}

// ---------------------------------------------------------------------------
// gather pipeline helpers — HALF-GROUP (4 edges x 2 rows = 8 loads) so the
// ping-pong staging is 32 VGPRs total (R5's full-group version was 64 and
// spilled under the (512,6) cap of 85 -> scratch round-trips -> regression).
// ---------------------------------------------------------------------------
__device__ __forceinline__ void load_hg(const int2* __restrict__ e0r,
                                        const int2* __restrict__ e1r,
                                        const unsigned int* __restrict__ h8,
                                        int lane, int base,
                                        unsigned int (&x0)[4], unsigned int (&x1)[4],
                                        float (&s0)[4], float (&s1)[4]) {
    #pragma unroll
    for (int u = 0; u < 4; ++u) {
        int2 p = e0r[base + u];            // uniform -> s_load_dwordx2
        int2 q = e1r[base + u];
        s0[u] = __int_as_float(p.y);
        s1[u] = __int_as_float(q.y);
        x0[u] = h8[(size_t)p.x * 64 + lane];
        x1[u] = h8[(size_t)q.x * 64 + lane];
    }
}

__device__ __forceinline__ void proc_hg(const unsigned int (&x0)[4],
                                        const unsigned int (&x1)[4],
                                        const float (&s0)[4], const float (&s1)[4],
                                        float4& a0, float4& a1) {
    #pragma unroll
    for (int u = 0; u < 4; ++u) {
        floatx2 lo = __builtin_amdgcn_cvt_pk_f32_fp8(x0[u], false);
        floatx2 hi = __builtin_amdgcn_cvt_pk_f32_fp8(x0[u], true);
        a0.x = fmaf(s0[u], lo.x, a0.x);
        a0.y = fmaf(s0[u], lo.y, a0.y);
        a0.z = fmaf(s0[u], hi.x, a0.z);
        a0.w = fmaf(s0[u], hi.y, a0.w);
        lo = __builtin_amdgcn_cvt_pk_f32_fp8(x1[u], false);
        hi = __builtin_amdgcn_cvt_pk_f32_fp8(x1[u], true);
        a1.x = fmaf(s1[u], lo.x, a1.x);
        a1.y = fmaf(s1[u], lo.y, a1.y);
        a1.z = fmaf(s1[u], hi.x, a1.z);
        a1.w = fmaf(s1[u], hi.y, a1.w);
    }
}

// ---------------------------------------------------------------------------
// layer_fused: block = 16 rows (grid 625), 8 waves (512 thr).
// Phase 1: wave handles 2 rows interleaved; ping-pong pipelined gather at
//          half-group (4-edge) granularity: next 8 loads issued while current
//          8 are consumed -> L2/LLC latency exposed once per row-pair.
//          FMA order per accumulator identical to the proven kernel.
// Phase 2: wave handles 2 col-tiles; out = relu(sup @ M), M pre-folded.
// LAST: out tile -> LDS fp32, in-block logits + log_softmax -> out.
// ---------------------------------------------------------------------------
template<bool LAST>
__global__ __launch_bounds__(512, 6) void layer_fused(const unsigned int* __restrict__ h8,
                                                      const unsigned short* __restrict__ h0b,
                                                      const float* __restrict__ dinv,
                                                      const int* __restrict__ cnt,
                                                      const int2* __restrict__ es,
                                                      const unsigned short* __restrict__ Mt,
                                                      const float* __restrict__ w1,
                                                      const float* __restrict__ b1,
                                                      unsigned char* __restrict__ h8_out,
                                                      float* __restrict__ out) {
    __shared__ unsigned short supb[16][264];
    __shared__ float hs[LAST ? 16 * 264 : 4];

    int t = threadIdx.x;
    int wv = __builtin_amdgcn_readfirstlane(t >> 6);   // wave-uniform in SGPR
    int lane = t & 63;
    int r0 = blockIdx.x * 16;

    // ---- phase 1: pipelined fp8 gather + mix -> supb (LDS) ----
    int lr0 = wv * 2, lr1 = lr0 + 1;
    int i0 = r0 + lr0, i1 = r0 + lr1;

    // independent loads issued first (retire earliest; no pipeline impact)
    unsigned int su0 = h8[(size_t)i0 * 64 + lane];
    unsigned int su1 = h8[(size_t)i1 * 64 + lane];
    ushort4v h0v0 = ((const ushort4v*)h0b)[(size_t)i0 * 64 + lane];
    ushort4v h0v1 = ((const ushort4v*)h0b)[(size_t)i1 * 64 + lane];

    float di0 = dinv[i0], di1 = dinv[i1];
    int dA = (cnt[i0] + 7) & ~7, dB = (cnt[i1] + 7) & ~7;
    int dm = dA > dB ? dA : dB;                 // padded entries are x0.0
    const int2* e0r = es + (size_t)i0 * MAXDEG;
    const int2* e1r = es + (size_t)i1 * MAXDEG;

    // self term (identical order to proven kernel: acc init = di * self)
    floatx2 slo = __builtin_amdgcn_cvt_pk_f32_fp8(su0, false);
    floatx2 shi = __builtin_amdgcn_cvt_pk_f32_fp8(su0, true);
    float4 a0, a1;
    a0.x = di0 * slo.x; a0.y = di0 * slo.y; a0.z = di0 * shi.x; a0.w = di0 * shi.y;
    slo = __builtin_amdgcn_cvt_pk_f32_fp8(su1, false);
    shi = __builtin_amdgcn_cvt_pk_f32_fp8(su1, true);
    a1.x = di1 * slo.x; a1.y = di1 * slo.y; a1.z = di1 * shi.x; a1.w = di1 * shi.y;

    unsigned int xA0[4], xA1[4], xB0[4], xB1[4];
    float sA0[4], sA1[4], sB0[4], sB1[4];
    int nh = dm >> 2;                           // half-groups; even; 0 if isolated
    if (nh > 0) {
        load_hg(e0r, e1r, h8, lane, 0, xA0, xA1, sA0, sA1);
        bool useA = true;
        #pragma unroll 1
        for (int g = 1; g < nh; ++g) {
            if (useA) {
                load_hg(e0r, e1r, h8, lane, g << 2, xB0, xB1, sB0, sB1);
                proc_hg(xA0, xA1, sA0, sA1, a0, a1);
            } else {
                load_hg(e0r, e1r, h8, lane, g << 2, xA0, xA1, sA0, sA1);
                proc_hg(xB0, xB1, sB0, sB1, a0, a1);
            }
            useA = !useA;
        }
        if (useA) proc_hg(xA0, xA1, sA0, sA1, a0, a1);
        else      proc_hg(xB0, xB1, sB0, sB1, a0, a1);
    }

    ushort4v ob;
    ob.x = f2bf(0.9f * (di0 * a0.x) + 0.1f * bf2f(h0v0.x));
    ob.y = f2bf(0.9f * (di0 * a0.y) + 0.1f * bf2f(h0v0.y));
    ob.z = f2bf(0.9f * (di0 * a0.z) + 0.1f * bf2f(h0v0.z));
    ob.w = f2bf(0.9f * (di0 * a0.w) + 0.1f * bf2f(h0v0.w));
    *(ushort4v*)&supb[lr0][4 * lane] = ob;
    ob.x = f2bf(0.9f * (di1 * a1.x) + 0.1f * bf2f(h0v1.x));
    ob.y = f2bf(0.9f * (di1 * a1.y) + 0.1f * bf2f(h0v1.y));
    ob.z = f2bf(0.9f * (di1 * a1.z) + 0.1f * bf2f(h0v1.z));
    ob.w = f2bf(0.9f * (di1 * a1.w) + 0.1f * bf2f(h0v1.w));
    *(ushort4v*)&supb[lr1][4 * lane] = ob;
    __syncthreads();

    // ---- phase 2: MFMA GEMM, epilogue = relu only (residual folded in M) ----
    int lrow = lane & 15, quad = lane >> 4;
    bf16x8 a[8];
    #pragma unroll
    for (int f = 0; f < 8; ++f)
        a[f] = *(const bf16x8*)&supb[lrow][quad * 8 + f * 32];

    #pragma unroll 1
    for (int n = 0; n < 2; ++n) {
        int nt = wv * 2 + n;
        floatx4 acc = {0.f, 0.f, 0.f, 0.f};
        const unsigned short* wrow = Mt + (size_t)(nt * 16 + lrow) * NHID + quad * 8;
        #pragma unroll
        for (int f = 0; f < 8; ++f) {
            bf16x8 b = *(const bf16x8*)(wrow + f * 32);
            acc = __builtin_amdgcn_mfma_f32_16x16x32_bf16(a[f], b, acc, 0, 0, 0);
        }
        int col = nt * 16 + lrow;
        #pragma unroll
        for (int r = 0; r < 4; ++r) {
            int lr2 = quad * 4 + r;
            float o = fmaxf(acc[r], 0.f);
            if (LAST) {
                hs[lr2 * 264 + col] = o;
            } else {
                h8_out[(size_t)(r0 + lr2) * NHID + col] = f2fp8(o);
            }
        }
    }

    // ---- phase 3 (LAST only): logits + log_softmax, in-block ----
    if (LAST) {
        __syncthreads();
        #pragma unroll 1
        for (int rr = 0; rr < 2; ++rr) {
            int lr = wv * 2 + rr;
            const float* hr = hs + lr * 264;
            float logit = -1e30f;
            if (lane < NCLASS) {
                float acc = b1[lane];
                #pragma unroll 8
                for (int k = 0; k < NHID; ++k)
                    acc = fmaf(hr[k], w1[k * NCLASS + lane], acc);
                logit = acc;
            }
            float m = logit;
            #pragma unroll
            for (int off = 32; off > 0; off >>= 1)
                m = fmaxf(m, __shfl_xor(m, off, 64));
            float e = (lane < NCLASS) ? expf(logit - m) : 0.0f;
            float ssum = e;
            #pragma unroll
            for (int off = 32; off > 0; off >>= 1)
                ssum += __shfl_xor(ssum, off, 64);
            float lse = m + logf(ssum);
            if (lane < NCLASS)
                out[(size_t)(r0 + lr) * NCLASS + lane] = logit - lse;
        }
    }
}

// ---------------------------------------------------------------------------
extern "C" void kernel_launch(void* const* d_in, const int* in_sizes, int n_in,
                              void* d_out, int out_size, void* d_ws, size_t ws_size,
                              hipStream_t stream) {
    const float* x      = (const float*)d_in[0];
    const float* adj    = (const float*)d_in[1];
    const float* w0     = (const float*)d_in[2];
    const float* b0     = (const float*)d_in[3];
    const float* conv_w = (const float*)d_in[4];
    const float* w1     = (const float*)d_in[5];
    const float* b1     = (const float*)d_in[6];
    float* out = (float*)d_out;

    char* ws = (char*)d_ws;
    size_t off = 0;
    auto alloc = [&](size_t bytes) -> void* {
        void* p = ws + off;
        off = (off + bytes + 255) & ~(size_t)255;
        return p;
    };
    float*          dinv  = (float*)alloc((size_t)NN * 4);
    int*            cnt   = (int*)  alloc((size_t)NN * 4);
    int*            ell   = (int*)  alloc((size_t)NN * MAXDEG * 4);
    int2*           es    = (int2*) alloc((size_t)NN * MAXDEG * 8);
    unsigned short* xb    = (unsigned short*)alloc((size_t)NN * NFEAT * 2);
    unsigned short* w0t   = (unsigned short*)alloc((size_t)NFEAT * NHID * 2);
    unsigned short* Mt    = (unsigned short*)alloc((size_t)NLAYERS * NHID * NHID * 2);
    unsigned short* h0b   = (unsigned short*)alloc((size_t)NN * NHID * 2);
    unsigned int*   h08   = (unsigned int*)alloc((size_t)NN * NHID);
    unsigned int*   hP8   = (unsigned int*)alloc((size_t)NN * NHID);
    unsigned int*   hQ8   = (unsigned int*)alloc((size_t)NN * NHID);

    build_graph<<<NN, 256, 0, stream>>>(adj, cnt, ell, dinv);
    prep_all<<<CVX_BLOCKS + PW_BLOCKS + PE_BLOCKS, 256, 0, stream>>>(
        x, xb, w0, conv_w, w0t, Mt, ell, cnt, dinv, es);
    gemm0_mfma<<<NN / 16, 512, 0, stream>>>(xb, w0t, b0, h0b, (unsigned char*)h08);

    const unsigned int* hc8 = h08;
    for (int l = 0; l < NLAYERS; ++l) {
        unsigned int* nxt = (l & 1) ? hQ8 : hP8;
        const unsigned short* wt = Mt + (size_t)l * NHID * NHID;
        if (l == NLAYERS - 1)
            layer_fused<true><<<NN / 16, 512, 0, stream>>>(hc8, h0b, dinv, cnt, es, wt, w1, b1, nullptr, out);
        else
            layer_fused<false><<<NN / 16, 512, 0, stream>>>(hc8, h0b, dinv, cnt, es, wt, nullptr, nullptr, (unsigned char*)nxt, nullptr);
        hc8 = nxt;
    }
}